// Round 16
// baseline (253.103 us; speedup 1.0000x reference)
//
#include <hip/hip_runtime.h>
#include <math.h>

#define N_NODES 50000
#define N_EDGES 800000
#define ETOT    (N_EDGES + N_NODES)   // self-loops appended
#define GGRAPHS 64
#define EPS_BN  1e-5f

typedef __attribute__((ext_vector_type(8))) short short8;
typedef __attribute__((ext_vector_type(4))) float f32x4;
typedef __attribute__((ext_vector_type(2))) float f32x2;

__device__ __forceinline__ unsigned short f2bf(float f) {
    union { float f; unsigned u; } v; v.f = f;
    unsigned r = v.u + 0x7fffu + ((v.u >> 16) & 1u);   // round-nearest-even
    return (unsigned short)(r >> 16);
}
__device__ __forceinline__ float leaky(float e) {
    return fmaxf(e, 0.2f * e);
}
// pack 4 f32 -> 4 fp8 (e4m3, OCP on gfx950)
__device__ __forceinline__ unsigned pack4_fp8(float a, float b, float c, float d) {
    int v = __builtin_amdgcn_cvt_pk_fp8_f32(a, b, 0, false);
    v = __builtin_amdgcn_cvt_pk_fp8_f32(c, d, v, true);
    return (unsigned)v;
}

// bucket-sort CSR build params
#define NBUK 196                       // dst >> 8
#define EPB  4096                      // edges per fill block
#define NBLK2 ((ETOT + EPB - 1) / EPB) // 208
#define CAPR 6144                      // fixed pairs region per bucket (mean 4352, +28 sigma)
#define CAP  6144

// mega-kernel block ranges
#define PREPW_T (16384 + 320)
#define NPREPW ((PREPW_T + 255) / 256) // 66
#define NT1B 782                       // gemm1 tile blocks (4 tiles each, 3125 tiles)
#define NMEGA (NBLK2 + NPREPW + NT1B)  // 1056

// ---------------- MEGA: bucket fill | W2T+BN prep | gemm1 ----------------

__global__ __launch_bounds__(256)
void k_mega(const float* __restrict__ x, const int* __restrict__ ei,
            const float* __restrict__ W1, const float* __restrict__ W2,
            const float* __restrict__ b1, const float* __restrict__ g1,
            const float* __restrict__ be1, const float* __restrict__ m1,
            const float* __restrict__ v1,
            const float* __restrict__ b2, const float* __restrict__ g2,
            const float* __restrict__ be2, const float* __restrict__ m2,
            const float* __restrict__ v2,
            const float* __restrict__ a_s, const float* __restrict__ a_d,
            unsigned short* __restrict__ W2T,
            float* __restrict__ A1s, float* __restrict__ B1s,
            float* __restrict__ A2s, float* __restrict__ B2s,
            int* __restrict__ gcur, unsigned* __restrict__ pairs,
            unsigned char* __restrict__ h1f8,
            float* __restrict__ es1, float* __restrict__ ed1) {
    __shared__ unsigned short W1T[256 * 72];     // gemm1 branch (36.9 KB)
    __shared__ int lcnt[NBUK];                   // fill branch
    __shared__ int lbase[NBUK];
    int t = threadIdx.x;
    int b = blockIdx.x;

    if (b < NBLK2) {
        // ---- bucket fill: count in LDS, reserve global range, dense scatter ----
        for (int i = t; i < NBUK; i += 256) lcnt[i] = 0;
        __syncthreads();
        int e0 = b * EPB;
        int ds[16], ss[16];
#pragma unroll
        for (int j = 0; j < 16; ++j) {
            int e = e0 + j * 256 + t;
            int s = -1, d = -1;
            if (e < ETOT) {
                if (e < N_EDGES) { s = ei[e]; d = ei[N_EDGES + e]; }
                else             { s = d = e - N_EDGES; }
                atomicAdd(&lcnt[d >> 8], 1);
            }
            ds[j] = d; ss[j] = s;
        }
        __syncthreads();
        for (int i = t; i < NBUK; i += 256) {
            int c = lcnt[i];
            lbase[i] = i * CAPR + (c ? atomicAdd(&gcur[i], c) : 0);
        }
        __syncthreads();
#pragma unroll
        for (int j = 0; j < 16; ++j) {
            if (ds[j] >= 0) {
                int bk = ds[j] >> 8;
                int pos = atomicAdd(&lbase[bk], 1);
                if (pos < (bk + 1) * CAPR)
                    pairs[pos] = (unsigned)ss[j] | ((unsigned)(ds[j] & 255) << 16);
            }
        }
        return;
    }
    if (b < NBLK2 + NPREPW) {
        // ---- W2T (perm rows) + BN folds ----
        int t2 = (b - NBLK2) * 256 + t;
        if (t2 < 16384) {
            int n = t2 >> 8, kp = t2 & 255;     // W2T[n*256+k'] = W2[real(k')*64+n]
            int rk = (kp & 15) * 16 + (kp >> 4);
            W2T[t2] = f2bf(W2[rk * 64 + n]);
        } else if (t2 < 16384 + 256) {
            int z = t2 - 16384;                 // hb slot z holds real (z&15)*16+(z>>4)
            int r = (z & 15) * 16 + (z >> 4);
            float A = g1[r] * rsqrtf(v1[r] + EPS_BN);
            A1s[z] = A;
            B1s[z] = (b1[r] - m1[r]) * A + be1[r];
        } else if (t2 < PREPW_T) {
            int z = t2 - 16384 - 256;           // pooled slot z holds real (z&3)*16+(z>>2)
            int r = (z & 3) * 16 + (z >> 2);
            float A = g2[r] * rsqrtf(v2[r] + EPS_BN);
            A2s[z] = A;
            B2s[z] = (b2[r] - m2[r]) * A + be2[r];
        }
        return;
    }
    // ---- gemm1: h1(fp8, perm) = x @ W1, scores es1/ed1 ----
    for (int k = 0; k < 64; ++k)
        W1T[t * 72 + k] = f2bf(W1[k * 256 + t]);
    __syncthreads();
    int wid = t >> 6, lane = t & 63;
    int quad = lane >> 4, col = lane & 15;
    float as_r[16], ad_r[16];
#pragma unroll
    for (int i = 0; i < 16; ++i) {
        as_r[i] = a_s[i * 16 + col];
        ad_r[i] = a_d[i * 16 + col];
    }
    int tile = (b - NBLK2 - NPREPW) * 4 + wid;
    if (tile >= 3125) return;
    int base = tile * 16;
    const float* xr = &x[(size_t)(base + col) * 64 + quad * 8];
    float4 u0 = *(const float4*)xr;
    float4 u1 = *(const float4*)(xr + 4);
    float4 u2 = *(const float4*)(xr + 32);
    float4 u3 = *(const float4*)(xr + 36);
    short8 a0, a1;
    a0[0] = (short)f2bf(u0.x); a0[1] = (short)f2bf(u0.y);
    a0[2] = (short)f2bf(u0.z); a0[3] = (short)f2bf(u0.w);
    a0[4] = (short)f2bf(u1.x); a0[5] = (short)f2bf(u1.y);
    a0[6] = (short)f2bf(u1.z); a0[7] = (short)f2bf(u1.w);
    a1[0] = (short)f2bf(u2.x); a1[1] = (short)f2bf(u2.y);
    a1[2] = (short)f2bf(u2.z); a1[3] = (short)f2bf(u2.w);
    a1[4] = (short)f2bf(u3.x); a1[5] = (short)f2bf(u3.y);
    a1[6] = (short)f2bf(u3.z); a1[7] = (short)f2bf(u3.w);
    f32x4 acc[16];
#pragma unroll
    for (int nt = 0; nt < 16; ++nt) acc[nt] = (f32x4){0.f, 0.f, 0.f, 0.f};
#pragma unroll
    for (int nt = 0; nt < 16; ++nt) {
        short8 b0 = *(const short8*)&W1T[(nt * 16 + col) * 72 + quad * 8];
        short8 b1 = *(const short8*)&W1T[(nt * 16 + col) * 72 + 32 + quad * 8];
        acc[nt] = __builtin_amdgcn_mfma_f32_16x16x32_bf16(a0, b0, acc[nt], 0, 0, 0);
        acc[nt] = __builtin_amdgcn_mfma_f32_16x16x32_bf16(a1, b1, acc[nt], 0, 0, 0);
    }
    float esp[16], edp[16];
#pragma unroll
    for (int i = 0; i < 16; ++i) { esp[i] = 0.f; edp[i] = 0.f; }
#pragma unroll
    for (int nt = 0; nt < 16; ++nt) {
        int hd = nt >> 2;
#pragma unroll
        for (int r = 0; r < 4; ++r) {
            esp[hd * 4 + r] += acc[nt][r] * as_r[nt];
            edp[hd * 4 + r] += acc[nt][r] * ad_r[nt];
        }
    }
#pragma unroll
    for (int i = 0; i < 16; ++i) {
        float v = esp[i], w = edp[i];
#pragma unroll
        for (int m = 1; m <= 8; m <<= 1) { v += __shfl_xor(v, m); w += __shfl_xor(w, m); }
        esp[i] = v; edp[i] = w;
    }
    if (col == 0) {
#pragma unroll
        for (int hd = 0; hd < 4; ++hd)
#pragma unroll
            for (int r = 0; r < 4; ++r) {
                int node = base + quad * 4 + r;
                es1[node * 4 + hd] = esp[hd * 4 + r];
                ed1[node * 4 + hd] = edp[hd * 4 + r];
            }
    }
#pragma unroll
    for (int r = 0; r < 4; ++r) {
        uint4 pk;
        pk.x = pack4_fp8(acc[0][r],  acc[1][r],  acc[2][r],  acc[3][r]);
        pk.y = pack4_fp8(acc[4][r],  acc[5][r],  acc[6][r],  acc[7][r]);
        pk.z = pack4_fp8(acc[8][r],  acc[9][r],  acc[10][r], acc[11][r]);
        pk.w = pack4_fp8(acc[12][r], acc[13][r], acc[14][r], acc[15][r]);
        *(uint4*)&h1f8[(size_t)(base + quad * 4 + r) * 256 + col * 16] = pk;
    }
}

// ---------------- per-bucket LDS sort -> coalesced csr + offs ----------------

__global__ __launch_bounds__(256)
void k_csr(const unsigned* __restrict__ pairs, const int* __restrict__ gcur,
           int* __restrict__ offs, unsigned short* __restrict__ csr) {
    __shared__ unsigned sp[CAP];
    __shared__ unsigned short lc[CAP];
    __shared__ int c256[256];
    __shared__ int o256[256];
    __shared__ int s[256];
    int b = blockIdx.x, t = threadIdx.x;
    int v = (t < NBUK) ? gcur[t] : 0;
    s[t] = v; __syncthreads();
    for (int d2 = 1; d2 < 256; d2 <<= 1) {
        int add = (t >= d2) ? s[t - d2] : 0;
        __syncthreads();
        s[t] += add;
        __syncthreads();
    }
    int gb = gcur[b];
    int base = s[b] - gb;
    int total = s[NBUK - 1];
    if (b == NBUK - 1 && t == 0) offs[N_NODES] = total;
    __syncthreads();
    int n = min(gb, CAP);
    int node = b * 256 + t;
    const unsigned* reg = pairs + (size_t)b * CAPR;
    for (int i = t; i < n; i += 256) sp[i] = reg[i];
    c256[t] = 0;
    __syncthreads();
    for (int i = t; i < n; i += 256) atomicAdd(&c256[(sp[i] >> 16) & 255], 1);
    __syncthreads();
    int v2 = c256[t];
    s[t] = v2; __syncthreads();
    for (int d2 = 1; d2 < 256; d2 <<= 1) {
        int add = (t >= d2) ? s[t - d2] : 0;
        __syncthreads();
        s[t] += add;
        __syncthreads();
    }
    int myoff = s[t] - v2;
    o256[t] = myoff;
    if (node < N_NODES) offs[node] = base + myoff;
    __syncthreads();
    for (int i = t; i < n; i += 256) {
        unsigned p = sp[i];
        int pos = atomicAdd(&o256[(p >> 16) & 255], 1);
        lc[pos] = (unsigned short)(p & 0xffff);
    }
    __syncthreads();
    for (int i = t; i < n; i += 256) csr[base + i] = lc[i];
}

// ---------------- fused GAT1 + GEMM2 (phase 1 pipelined 2x: 8 edges/iter) ----

__global__ __launch_bounds__(256)
void k_gat1g2(const unsigned char* __restrict__ h1f8, const float* __restrict__ es1,
              const float* __restrict__ ed1, const int* __restrict__ offs,
              const unsigned short* __restrict__ csr,
              const float* __restrict__ A1s, const float* __restrict__ B1s,
              const unsigned short* __restrict__ W2Tg,
              const float* __restrict__ a_s2, const float* __restrict__ a_d2,
              unsigned char* __restrict__ h2f8, float* __restrict__ es2,
              float* __restrict__ ed2) {
    __shared__ unsigned short hbt[16][264];
    __shared__ float esps[4][16], edps[4][16];
    __shared__ uint4 h2t4[64];                  // 16 nodes x 64 B
    unsigned char* h2t = (unsigned char*)h2t4;
    int tid = threadIdx.x;
    int l = tid & 63;
    int gbase = l & 48;
    int q = tid & 15;
    int dl = tid >> 4;
    int nbase = blockIdx.x * 16;
    int d = nbase + dl;
    int start = offs[d], deg = offs[d + 1] - start;
    int e4 = q >> 2, hd = q & 3;
    float edv = ed1[d * 4 + hd];
    const unsigned char* hrow = h1f8 + q * 16;
    float a[16];
#pragma unroll
    for (int i = 0; i < 16; ++i) a[i] = 0.f;
    float wsum = 0.f;
    for (int c0 = 0; c0 < deg; c0 += 8) {
        int idx0 = c0 + e4;
        int idx1 = c0 + 4 + e4;
        int s0 = csr[start + min(idx0, deg - 1)];
        int s1 = csr[start + min(idx1, deg - 1)];
        float w0l = (idx0 < deg) ? __expf(leaky(es1[s0 * 4 + hd] + edv)) : 0.f;
        float w1l = (idx1 < deg) ? __expf(leaky(es1[s1 * 4 + hd] + edv)) : 0.f;
        wsum += w0l + w1l;
        int se[8];
#pragma unroll
        for (int e = 0; e < 4; ++e) se[e] = __shfl(s0, gbase | (e << 2));
#pragma unroll
        for (int e = 4; e < 8; ++e) se[e] = __shfl(s1, gbase | ((e - 4) << 2));
        uint4 rv[8];
#pragma unroll
        for (int e = 0; e < 8; ++e)
            rv[e] = *(const uint4*)(hrow + ((size_t)(unsigned)se[e] << 8));
#pragma unroll
        for (int e = 0; e < 8; ++e) {
            int lsrc = gbase | ((e & 3) << 2);
            float wl = (e < 4) ? w0l : w1l;
            float w0 = __shfl(wl, lsrc | 0);
            float w1 = __shfl(wl, lsrc | 1);
            float w2 = __shfl(wl, lsrc | 2);
            float w3 = __shfl(wl, lsrc | 3);
            f32x2 p;
            p = __builtin_amdgcn_cvt_pk_f32_fp8((int)rv[e].x, false); a[0]  += w0 * p.x; a[1]  += w0 * p.y;
            p = __builtin_amdgcn_cvt_pk_f32_fp8((int)rv[e].x, true);  a[2]  += w0 * p.x; a[3]  += w0 * p.y;
            p = __builtin_amdgcn_cvt_pk_f32_fp8((int)rv[e].y, false); a[4]  += w1 * p.x; a[5]  += w1 * p.y;
            p = __builtin_amdgcn_cvt_pk_f32_fp8((int)rv[e].y, true);  a[6]  += w1 * p.x; a[7]  += w1 * p.y;
            p = __builtin_amdgcn_cvt_pk_f32_fp8((int)rv[e].z, false); a[8]  += w2 * p.x; a[9]  += w2 * p.y;
            p = __builtin_amdgcn_cvt_pk_f32_fp8((int)rv[e].z, true);  a[10] += w2 * p.x; a[11] += w2 * p.y;
            p = __builtin_amdgcn_cvt_pk_f32_fp8((int)rv[e].w, false); a[12] += w3 * p.x; a[13] += w3 * p.y;
            p = __builtin_amdgcn_cvt_pk_f32_fp8((int)rv[e].w, true);  a[14] += w3 * p.x; a[15] += w3 * p.y;
        }
    }
    wsum += __shfl_xor(wsum, 4);
    wsum += __shfl_xor(wsum, 8);
    float inv[4];
#pragma unroll
    for (int h = 0; h < 4; ++h) inv[h] = 1.f / __shfl(wsum, gbase | h);
#pragma unroll
    for (int i0 = 0; i0 < 4; ++i0) {
        float4 Av = *(const float4*)&A1s[q * 16 + i0 * 4];
        float4 Bv = *(const float4*)&B1s[q * 16 + i0 * 4];
        float o0 = a[i0 * 4 + 0] * inv[i0] * Av.x + Bv.x;
        float o1 = a[i0 * 4 + 1] * inv[i0] * Av.y + Bv.y;
        float o2 = a[i0 * 4 + 2] * inv[i0] * Av.z + Bv.z;
        float o3 = a[i0 * 4 + 3] * inv[i0] * Av.w + Bv.w;
        o0 = (o0 > 0.f) ? o0 : expm1f(o0);
        o1 = (o1 > 0.f) ? o1 : expm1f(o1);
        o2 = (o2 > 0.f) ? o2 : expm1f(o2);
        o3 = (o3 > 0.f) ? o3 : expm1f(o3);
        ushort4 ov;
        ov.x = f2bf(o0); ov.y = f2bf(o1); ov.z = f2bf(o2); ov.w = f2bf(o3);
        *(ushort4*)&hbt[dl][q * 16 + i0 * 4] = ov;
    }
    __syncthreads();
    // ---- phase 2: gemm2 for this 16-node tile ----
    int w = tid >> 6;
    int quad = l >> 4, col = l & 15;
    short8 af[8];
#pragma unroll
    for (int kk = 0; kk < 8; ++kk)
        af[kk] = *(const short8*)&hbt[col][kk * 32 + quad * 8];
    f32x4 acc = (f32x4){0.f, 0.f, 0.f, 0.f};
#pragma unroll
    for (int kk = 0; kk < 8; ++kk) {
        short8 b = *(const short8*)&W2Tg[(w * 16 + col) * 256 + kk * 32 + quad * 8];
        acc = __builtin_amdgcn_mfma_f32_16x16x32_bf16(af[kk], b, acc, 0, 0, 0);
    }
    float asw = a_s2[w * 16 + col], adw = a_d2[w * 16 + col];
    float esp[4], edp[4];
#pragma unroll
    for (int r = 0; r < 4; ++r) { esp[r] = acc[r] * asw; edp[r] = acc[r] * adw; }
#pragma unroll
    for (int r = 0; r < 4; ++r) {
#pragma unroll
        for (int m = 1; m <= 8; m <<= 1) {
            esp[r] += __shfl_xor(esp[r], m);
            edp[r] += __shfl_xor(edp[r], m);
        }
    }
    if (col == 0) {
#pragma unroll
        for (int r = 0; r < 4; ++r) {
            esps[w][quad * 4 + r] = esp[r];
            edps[w][quad * 4 + r] = edp[r];
        }
    }
#pragma unroll
    for (int r = 0; r < 4; ++r) {
        unsigned pk = pack4_fp8(acc[r], acc[r], acc[r], acc[r]);
        h2t[(quad * 4 + r) * 64 + col * 4 + w] = (unsigned char)(pk & 0xff);
    }
    __syncthreads();
    if (tid < 16) {
        es2[nbase + tid] = esps[0][tid] + esps[1][tid] + esps[2][tid] + esps[3][tid];
        ed2[nbase + tid] = edps[0][tid] + edps[1][tid] + edps[2][tid] + edps[3][tid];
    }
    if (tid < 64) {
        int node = tid >> 2, c = tid & 3;
        *(uint4*)&h2f8[(size_t)(nbase + node) * 64 + c * 16] = h2t4[node * 4 + c];
    }
}

// ---------------- fused GAT2 + mean-pool + (last block) MLP head ------------
// 8-lane groups, 32 nodes/block. After pooling atomics, the last block to
// finish computes the MLP head + log_softmax inline (device-scope counter).

__device__ int lower_bound_i(const int* a, int n, int key) {
    int lo = 0, hi = n;
    while (lo < hi) {
        int mid = (lo + hi) >> 1;
        if (a[mid] < key) lo = mid + 1; else hi = mid;
    }
    return lo;
}

#define NGAT2 ((N_NODES + 31) / 32)    // 1563

__global__ __launch_bounds__(256)
void k_gat2p(const unsigned char* __restrict__ h2f8, const float* __restrict__ es2,
             const float* __restrict__ ed2, const int* __restrict__ offs,
             const unsigned short* __restrict__ csr,
             const float* __restrict__ A2s, const float* __restrict__ B2s,
             const int* __restrict__ batch, float* __restrict__ pooled,
             int* __restrict__ counter,
             const float* __restrict__ lw1, const float* __restrict__ lb1,
             const float* __restrict__ lw2, const float* __restrict__ lb2,
             float* __restrict__ out) {
    __shared__ float ot[32][68];
    __shared__ int gbat[32];
    __shared__ int lastflag;
    int tid = threadIdx.x;
    int l = tid & 63;
    int gb8 = l & 56;                  // 8-lane group base within wave
    int p = l & 7;
    int nb = tid >> 3;                 // node index in block (0..31)
    int nbase = blockIdx.x * 32;
    int d = nbase + nb;
    bool valid = d < N_NODES;
    int dv = valid ? d : (N_NODES - 1);
    int start = offs[dv];
    int deg = valid ? (offs[dv + 1] - start) : 0;
    float edv = ed2[dv];
    const unsigned char* hrow = h2f8 + p * 8;
    float a[8];
#pragma unroll
    for (int i = 0; i < 8; ++i) a[i] = 0.f;
    float wsum = 0.f;
    for (int c0 = 0; c0 < deg; c0 += 16) {
        int idx0 = c0 + p;
        int idx1 = c0 + 8 + p;
        int s0 = csr[start + min(idx0, deg - 1)];
        int s1 = csr[start + min(idx1, deg - 1)];
        float w0l = (idx0 < deg) ? __expf(leaky(es2[s0] + edv)) : 0.f;
        float w1l = (idx1 < deg) ? __expf(leaky(es2[s1] + edv)) : 0.f;
        wsum += w0l + w1l;
        int se[16];
#pragma unroll
        for (int e = 0; e < 8; ++e) se[e] = __shfl(s0, gb8 | e);
#pragma unroll
        for (int e = 8; e < 16; ++e) se[e] = __shfl(s1, gb8 | (e - 8));
        uint2 rv[16];
#pragma unroll
        for (int e = 0; e < 16; ++e)
            rv[e] = *(const uint2*)(hrow + ((size_t)(unsigned)se[e] << 6));
#pragma unroll
        for (int e = 0; e < 16; ++e) {
            float wl = (e < 8) ? w0l : w1l;
            float we = __shfl(wl, gb8 | (e & 7));
            f32x2 pr;
            pr = __builtin_amdgcn_cvt_pk_f32_fp8((int)rv[e].x, false); a[0] += we * pr.x; a[1] += we * pr.y;
            pr = __builtin_amdgcn_cvt_pk_f32_fp8((int)rv[e].x, true);  a[2] += we * pr.x; a[3] += we * pr.y;
            pr = __builtin_amdgcn_cvt_pk_f32_fp8((int)rv[e].y, false); a[4] += we * pr.x; a[5] += we * pr.y;
            pr = __builtin_amdgcn_cvt_pk_f32_fp8((int)rv[e].y, true);  a[6] += we * pr.x; a[7] += we * pr.y;
        }
    }
    wsum += __shfl_xor(wsum, 1);
    wsum += __shfl_xor(wsum, 2);
    wsum += __shfl_xor(wsum, 4);       // group-complete denominator
    float inv = (wsum > 0.f) ? 1.f / wsum : 0.f;
    float4 Av0 = *(const float4*)&A2s[p * 8];
    float4 Bv0 = *(const float4*)&B2s[p * 8];
    float4 Av1 = *(const float4*)&A2s[p * 8 + 4];
    float4 Bv1 = *(const float4*)&B2s[p * 8 + 4];
    float4 o0, o1;
    if (valid) {
        o0.x = a[0] * inv * Av0.x + Bv0.x;
        o0.y = a[1] * inv * Av0.y + Bv0.y;
        o0.z = a[2] * inv * Av0.z + Bv0.z;
        o0.w = a[3] * inv * Av0.w + Bv0.w;
        o1.x = a[4] * inv * Av1.x + Bv1.x;
        o1.y = a[5] * inv * Av1.y + Bv1.y;
        o1.z = a[6] * inv * Av1.z + Bv1.z;
        o1.w = a[7] * inv * Av1.w + Bv1.w;
    } else {
        o0 = make_float4(0.f, 0.f, 0.f, 0.f);
        o1 = o0;
    }
    *(float4*)&ot[nb][p * 8] = o0;
    *(float4*)&ot[nb][p * 8 + 4] = o1;
    if (tid < 32) gbat[tid] = batch[min(nbase + tid, N_NODES - 1)];
    __syncthreads();
    if (tid < 64) {
        int ch = tid;
        int curg = gbat[0];
        float acc = 0.f;
#pragma unroll
        for (int n = 0; n < 32; ++n) {
            int g = gbat[n];
            if (g != curg) {
                atomicAdd(&pooled[curg * 64 + ch], acc);
                acc = 0.f;
                curg = g;
            }
            acc += ot[n][ch];
        }
        atomicAdd(&pooled[curg * 64 + ch], acc);
    }
    // ---- last-block MLP head ----
    __syncthreads();
    if (tid == 0) {
        __threadfence();
        int old = atomicAdd(counter, 1);
        lastflag = (old == NGAT2 - 1);
    }
    __syncthreads();
    if (!lastflag) return;
    if (tid >= GGRAPHS) return;
    int g = tid;
    int s0g = lower_bound_i(batch, N_NODES, g);
    int s1g = lower_bound_i(batch, N_NODES, g + 1);
    int cnt = s1g - s0g;
    float invc = 1.f / (float)((cnt > 0) ? cnt : 1);
    float pv[64];
#pragma unroll
    for (int c = 0; c < 64; ++c) {
        float x = __hip_atomic_load(&pooled[g * 64 + c], __ATOMIC_RELAXED,
                                    __HIP_MEMORY_SCOPE_AGENT);
        pv[c] = x * invc;
    }
    float z0 = lb2[0], z1 = lb2[1], z2 = lb2[2];
    for (int j = 0; j < 32; ++j) {
        float hj = lb1[j];
#pragma unroll
        for (int c = 0; c < 64; ++c) {
            int rc = (c & 3) * 16 + (c >> 2);    // slot c holds real channel rc
            hj += pv[c] * lw1[rc * 32 + j];
        }
        hj = fmaxf(hj, 0.f);
        z0 += hj * lw2[j * 3 + 0];
        z1 += hj * lw2[j * 3 + 1];
        z2 += hj * lw2[j * 3 + 2];
    }
    float m = fmaxf(z0, fmaxf(z1, z2));
    float lse = logf(expf(z0 - m) + expf(z1 - m) + expf(z2 - m)) + m;
    out[g * 3 + 0] = z0 - lse;
    out[g * 3 + 1] = z1 - lse;
    out[g * 3 + 2] = z2 - lse;
}

// ---------------- launch ----------------

extern "C" void kernel_launch(void* const* d_in, const int* in_sizes, int n_in,
                              void* d_out, int out_size, void* d_ws, size_t ws_size,
                              hipStream_t stream) {
    (void)in_sizes; (void)n_in; (void)out_size; (void)ws_size;
    const float* x    = (const float*)d_in[0];
    const int*   ei   = (const int*)d_in[1];
    const int*   batch= (const int*)d_in[2];
    const float* W1   = (const float*)d_in[3];
    const float* a_s1 = (const float*)d_in[4];
    const float* a_d1 = (const float*)d_in[5];
    const float* b1   = (const float*)d_in[6];
    const float* g1   = (const float*)d_in[7];
    const float* be1  = (const float*)d_in[8];
    const float* m1   = (const float*)d_in[9];
    const float* v1   = (const float*)d_in[10];
    const float* W2   = (const float*)d_in[11];
    const float* a_s2 = (const float*)d_in[12];
    const float* a_d2 = (const float*)d_in[13];
    const float* b2   = (const float*)d_in[14];
    const float* g2   = (const float*)d_in[15];
    const float* be2  = (const float*)d_in[16];
    const float* m2   = (const float*)d_in[17];
    const float* v2   = (const float*)d_in[18];
    const float* lw1  = (const float*)d_in[19];
    const float* lb1  = (const float*)d_in[20];
    const float* lw2  = (const float*)d_in[21];
    const float* lb2  = (const float*)d_in[22];
    float* out = (float*)d_out;

    char* ws = (char*)d_ws;
    size_t off = 0;
    auto alloc = [&](size_t bytes) -> void* {
        void* p = ws + off;
        off += (bytes + 255) & ~(size_t)255;
        return p;
    };
    // pooled + gcur/counter adjacent: one memset covers all (16384 + 1024 B)
    float* pooled = (float*)alloc((size_t)GGRAPHS * 64 * 4);     // 16384 B
    int*   gcur   = (int*)alloc((size_t)(NBUK + 1) * 4);         // -> 1024 B slot
    int*   counter = gcur + NBUK;                                // within memset span
    unsigned short* W2T = (unsigned short*)alloc((size_t)16384 * 2);
    unsigned char*  h1  = (unsigned char*)alloc((size_t)N_NODES * 256);   // fp8 perm
    unsigned char*  h2  = (unsigned char*)alloc((size_t)N_NODES * 64);    // fp8 perm
    float* es1  = (float*)alloc((size_t)N_NODES * 4 * 4);
    float* ed1  = (float*)alloc((size_t)N_NODES * 4 * 4);
    float* es2  = (float*)alloc((size_t)N_NODES * 4);
    float* ed2  = (float*)alloc((size_t)N_NODES * 4);
    float* A1s  = (float*)alloc(256 * 4);
    float* B1s  = (float*)alloc(256 * 4);
    float* A2s  = (float*)alloc(64 * 4);
    float* B2s  = (float*)alloc(64 * 4);
    int*   offs = (int*)alloc((size_t)(N_NODES + 1) * 4);
    unsigned short* csr = (unsigned short*)alloc((size_t)ETOT * 2);
    unsigned* pairs = (unsigned*)alloc((size_t)NBUK * CAPR * 4);

    const int ngat = 3125;                     // gat1g2: 16 nodes per block

    hipMemsetAsync(pooled, 0, 16384 + 1024, stream);   // pooled + gcur + counter
    k_mega<<<NMEGA, 256, 0, stream>>>(x, ei, W1, W2,
                                      b1, g1, be1, m1, v1,
                                      b2, g2, be2, m2, v2,
                                      a_s1, a_d1,
                                      W2T, A1s, B1s, A2s, B2s,
                                      gcur, pairs, h1, es1, ed1);
    k_csr<<<NBUK, 256, 0, stream>>>(pairs, gcur, offs, csr);
    k_gat1g2<<<ngat, 256, 0, stream>>>(h1, es1, ed1, offs, csr, A1s, B1s,
                                       W2T, a_s2, a_d2, h2, es2, ed2);
    k_gat2p<<<NGAT2, 256, 0, stream>>>(h2, es2, ed2, offs, csr, A2s, B2s,
                                       batch, pooled, counter,
                                       lw1, lb1, lw2, lb2, out);
}

// Round 17
// 223.693 us; speedup vs baseline: 1.1315x; 1.1315x over previous
//
#include <hip/hip_runtime.h>
#include <math.h>

#define N_NODES 50000
#define N_EDGES 800000
#define ETOT    (N_EDGES + N_NODES)   // self-loops appended
#define GGRAPHS 64
#define EPS_BN  1e-5f

typedef __attribute__((ext_vector_type(8))) short short8;
typedef __attribute__((ext_vector_type(4))) float f32x4;
typedef __attribute__((ext_vector_type(2))) float f32x2;

__device__ __forceinline__ unsigned short f2bf(float f) {
    union { float f; unsigned u; } v; v.f = f;
    unsigned r = v.u + 0x7fffu + ((v.u >> 16) & 1u);   // round-nearest-even
    return (unsigned short)(r >> 16);
}
__device__ __forceinline__ float leaky(float e) {
    return fmaxf(e, 0.2f * e);
}
// pack 4 f32 -> 4 fp8 (e4m3, OCP on gfx950)
__device__ __forceinline__ unsigned pack4_fp8(float a, float b, float c, float d) {
    int v = __builtin_amdgcn_cvt_pk_fp8_f32(a, b, 0, false);
    v = __builtin_amdgcn_cvt_pk_fp8_f32(c, d, v, true);
    return (unsigned)v;
}

// bucket-sort CSR build params
#define NBUK 196                       // dst >> 8
#define EPB  4096                      // edges per fill block
#define NBLK2 ((ETOT + EPB - 1) / EPB) // 208
#define CAPR 6144                      // fixed pairs region per bucket (mean 4352, +28 sigma)
#define CAP  6144

// mega-kernel block ranges
#define PREPW_T (16384 + 320)
#define NPREPW ((PREPW_T + 255) / 256) // 66
#define NT1B 782                       // gemm1 tile blocks (4 tiles each, 3125 tiles)
#define NMEGA (NBLK2 + NPREPW + NT1B)  // 1056

// ---------------- MEGA: bucket fill | W2T+BN prep | gemm1 ----------------

__global__ __launch_bounds__(256)
void k_mega(const float* __restrict__ x, const int* __restrict__ ei,
            const float* __restrict__ W1, const float* __restrict__ W2,
            const float* __restrict__ b1, const float* __restrict__ g1,
            const float* __restrict__ be1, const float* __restrict__ m1,
            const float* __restrict__ v1,
            const float* __restrict__ b2, const float* __restrict__ g2,
            const float* __restrict__ be2, const float* __restrict__ m2,
            const float* __restrict__ v2,
            const float* __restrict__ a_s, const float* __restrict__ a_d,
            unsigned short* __restrict__ W2T,
            float* __restrict__ A1s, float* __restrict__ B1s,
            float* __restrict__ A2s, float* __restrict__ B2s,
            int* __restrict__ gcur, unsigned* __restrict__ pairs,
            unsigned char* __restrict__ h1f8,
            float* __restrict__ es1, float* __restrict__ ed1) {
    __shared__ unsigned short W1T[256 * 72];     // gemm1 branch (36.9 KB)
    __shared__ int lcnt[NBUK];                   // fill branch
    __shared__ int lbase[NBUK];
    int t = threadIdx.x;
    int b = blockIdx.x;

    if (b < NBLK2) {
        // ---- bucket fill: count in LDS, reserve global range, dense scatter ----
        for (int i = t; i < NBUK; i += 256) lcnt[i] = 0;
        __syncthreads();
        int e0 = b * EPB;
        int ds[16], ss[16];
#pragma unroll
        for (int j = 0; j < 16; ++j) {
            int e = e0 + j * 256 + t;
            int s = -1, d = -1;
            if (e < ETOT) {
                if (e < N_EDGES) { s = ei[e]; d = ei[N_EDGES + e]; }
                else             { s = d = e - N_EDGES; }
                atomicAdd(&lcnt[d >> 8], 1);
            }
            ds[j] = d; ss[j] = s;
        }
        __syncthreads();
        for (int i = t; i < NBUK; i += 256) {
            int c = lcnt[i];
            lbase[i] = i * CAPR + (c ? atomicAdd(&gcur[i], c) : 0);
        }
        __syncthreads();
#pragma unroll
        for (int j = 0; j < 16; ++j) {
            if (ds[j] >= 0) {
                int bk = ds[j] >> 8;
                int pos = atomicAdd(&lbase[bk], 1);
                if (pos < (bk + 1) * CAPR)
                    pairs[pos] = (unsigned)ss[j] | ((unsigned)(ds[j] & 255) << 16);
            }
        }
        return;
    }
    if (b < NBLK2 + NPREPW) {
        // ---- W2T (perm rows) + BN folds ----
        int t2 = (b - NBLK2) * 256 + t;
        if (t2 < 16384) {
            int n = t2 >> 8, kp = t2 & 255;     // W2T[n*256+k'] = W2[real(k')*64+n]
            int rk = (kp & 15) * 16 + (kp >> 4);
            W2T[t2] = f2bf(W2[rk * 64 + n]);
        } else if (t2 < 16384 + 256) {
            int z = t2 - 16384;                 // hb slot z holds real (z&15)*16+(z>>4)
            int r = (z & 15) * 16 + (z >> 4);
            float A = g1[r] * rsqrtf(v1[r] + EPS_BN);
            A1s[z] = A;
            B1s[z] = (b1[r] - m1[r]) * A + be1[r];
        } else if (t2 < PREPW_T) {
            int z = t2 - 16384 - 256;           // pooled slot z holds real (z&3)*16+(z>>2)
            int r = (z & 3) * 16 + (z >> 2);
            float A = g2[r] * rsqrtf(v2[r] + EPS_BN);
            A2s[z] = A;
            B2s[z] = (b2[r] - m2[r]) * A + be2[r];
        }
        return;
    }
    // ---- gemm1: h1(fp8, perm) = x @ W1, scores es1/ed1 ----
    for (int k = 0; k < 64; ++k)
        W1T[t * 72 + k] = f2bf(W1[k * 256 + t]);
    __syncthreads();
    int wid = t >> 6, lane = t & 63;
    int quad = lane >> 4, col = lane & 15;
    float as_r[16], ad_r[16];
#pragma unroll
    for (int i = 0; i < 16; ++i) {
        as_r[i] = a_s[i * 16 + col];
        ad_r[i] = a_d[i * 16 + col];
    }
    int tile = (b - NBLK2 - NPREPW) * 4 + wid;
    if (tile >= 3125) return;
    int base = tile * 16;
    const float* xr = &x[(size_t)(base + col) * 64 + quad * 8];
    float4 u0 = *(const float4*)xr;
    float4 u1 = *(const float4*)(xr + 4);
    float4 u2 = *(const float4*)(xr + 32);
    float4 u3 = *(const float4*)(xr + 36);
    short8 a0, a1;
    a0[0] = (short)f2bf(u0.x); a0[1] = (short)f2bf(u0.y);
    a0[2] = (short)f2bf(u0.z); a0[3] = (short)f2bf(u0.w);
    a0[4] = (short)f2bf(u1.x); a0[5] = (short)f2bf(u1.y);
    a0[6] = (short)f2bf(u1.z); a0[7] = (short)f2bf(u1.w);
    a1[0] = (short)f2bf(u2.x); a1[1] = (short)f2bf(u2.y);
    a1[2] = (short)f2bf(u2.z); a1[3] = (short)f2bf(u2.w);
    a1[4] = (short)f2bf(u3.x); a1[5] = (short)f2bf(u3.y);
    a1[6] = (short)f2bf(u3.z); a1[7] = (short)f2bf(u3.w);
    f32x4 acc[16];
#pragma unroll
    for (int nt = 0; nt < 16; ++nt) acc[nt] = (f32x4){0.f, 0.f, 0.f, 0.f};
#pragma unroll
    for (int nt = 0; nt < 16; ++nt) {
        short8 b0 = *(const short8*)&W1T[(nt * 16 + col) * 72 + quad * 8];
        short8 b1 = *(const short8*)&W1T[(nt * 16 + col) * 72 + 32 + quad * 8];
        acc[nt] = __builtin_amdgcn_mfma_f32_16x16x32_bf16(a0, b0, acc[nt], 0, 0, 0);
        acc[nt] = __builtin_amdgcn_mfma_f32_16x16x32_bf16(a1, b1, acc[nt], 0, 0, 0);
    }
    float esp[16], edp[16];
#pragma unroll
    for (int i = 0; i < 16; ++i) { esp[i] = 0.f; edp[i] = 0.f; }
#pragma unroll
    for (int nt = 0; nt < 16; ++nt) {
        int hd = nt >> 2;
#pragma unroll
        for (int r = 0; r < 4; ++r) {
            esp[hd * 4 + r] += acc[nt][r] * as_r[nt];
            edp[hd * 4 + r] += acc[nt][r] * ad_r[nt];
        }
    }
#pragma unroll
    for (int i = 0; i < 16; ++i) {
        float v = esp[i], w = edp[i];
#pragma unroll
        for (int m = 1; m <= 8; m <<= 1) { v += __shfl_xor(v, m); w += __shfl_xor(w, m); }
        esp[i] = v; edp[i] = w;
    }
    if (col == 0) {
#pragma unroll
        for (int hd = 0; hd < 4; ++hd)
#pragma unroll
            for (int r = 0; r < 4; ++r) {
                int node = base + quad * 4 + r;
                es1[node * 4 + hd] = esp[hd * 4 + r];
                ed1[node * 4 + hd] = edp[hd * 4 + r];
            }
    }
#pragma unroll
    for (int r = 0; r < 4; ++r) {
        uint4 pk;
        pk.x = pack4_fp8(acc[0][r],  acc[1][r],  acc[2][r],  acc[3][r]);
        pk.y = pack4_fp8(acc[4][r],  acc[5][r],  acc[6][r],  acc[7][r]);
        pk.z = pack4_fp8(acc[8][r],  acc[9][r],  acc[10][r], acc[11][r]);
        pk.w = pack4_fp8(acc[12][r], acc[13][r], acc[14][r], acc[15][r]);
        *(uint4*)&h1f8[(size_t)(base + quad * 4 + r) * 256 + col * 16] = pk;
    }
}

// ---------------- per-bucket LDS sort -> coalesced csr + offs ----------------

__global__ __launch_bounds__(256)
void k_csr(const unsigned* __restrict__ pairs, const int* __restrict__ gcur,
           int* __restrict__ offs, unsigned short* __restrict__ csr) {
    __shared__ unsigned sp[CAP];
    __shared__ unsigned short lc[CAP];
    __shared__ int c256[256];
    __shared__ int o256[256];
    __shared__ int s[256];
    int b = blockIdx.x, t = threadIdx.x;
    int v = (t < NBUK) ? gcur[t] : 0;
    s[t] = v; __syncthreads();
    for (int d2 = 1; d2 < 256; d2 <<= 1) {
        int add = (t >= d2) ? s[t - d2] : 0;
        __syncthreads();
        s[t] += add;
        __syncthreads();
    }
    int gb = gcur[b];
    int base = s[b] - gb;
    int total = s[NBUK - 1];
    if (b == NBUK - 1 && t == 0) offs[N_NODES] = total;
    __syncthreads();
    int n = min(gb, CAP);
    int node = b * 256 + t;
    const unsigned* reg = pairs + (size_t)b * CAPR;
    for (int i = t; i < n; i += 256) sp[i] = reg[i];
    c256[t] = 0;
    __syncthreads();
    for (int i = t; i < n; i += 256) atomicAdd(&c256[(sp[i] >> 16) & 255], 1);
    __syncthreads();
    int v2 = c256[t];
    s[t] = v2; __syncthreads();
    for (int d2 = 1; d2 < 256; d2 <<= 1) {
        int add = (t >= d2) ? s[t - d2] : 0;
        __syncthreads();
        s[t] += add;
        __syncthreads();
    }
    int myoff = s[t] - v2;
    o256[t] = myoff;
    if (node < N_NODES) offs[node] = base + myoff;
    __syncthreads();
    for (int i = t; i < n; i += 256) {
        unsigned p = sp[i];
        int pos = atomicAdd(&o256[(p >> 16) & 255], 1);
        lc[pos] = (unsigned short)(p & 0xffff);
    }
    __syncthreads();
    for (int i = t; i < n; i += 256) csr[base + i] = lc[i];
}

// ---------------- fused GAT1 + GEMM2 (phase 1 pipelined 2x: 8 edges/iter) ----

__global__ __launch_bounds__(256)
void k_gat1g2(const unsigned char* __restrict__ h1f8, const float* __restrict__ es1,
              const float* __restrict__ ed1, const int* __restrict__ offs,
              const unsigned short* __restrict__ csr,
              const float* __restrict__ A1s, const float* __restrict__ B1s,
              const unsigned short* __restrict__ W2Tg,
              const float* __restrict__ a_s2, const float* __restrict__ a_d2,
              unsigned char* __restrict__ h2f8, float* __restrict__ es2,
              float* __restrict__ ed2) {
    __shared__ unsigned short hbt[16][264];
    __shared__ float esps[4][16], edps[4][16];
    __shared__ uint4 h2t4[64];                  // 16 nodes x 64 B
    unsigned char* h2t = (unsigned char*)h2t4;
    int tid = threadIdx.x;
    int l = tid & 63;
    int gbase = l & 48;
    int q = tid & 15;
    int dl = tid >> 4;
    int nbase = blockIdx.x * 16;
    int d = nbase + dl;
    int start = offs[d], deg = offs[d + 1] - start;
    int e4 = q >> 2, hd = q & 3;
    float edv = ed1[d * 4 + hd];
    const unsigned char* hrow = h1f8 + q * 16;
    float a[16];
#pragma unroll
    for (int i = 0; i < 16; ++i) a[i] = 0.f;
    float wsum = 0.f;
    for (int c0 = 0; c0 < deg; c0 += 8) {
        int idx0 = c0 + e4;
        int idx1 = c0 + 4 + e4;
        int s0 = csr[start + min(idx0, deg - 1)];
        int s1 = csr[start + min(idx1, deg - 1)];
        float w0l = (idx0 < deg) ? __expf(leaky(es1[s0 * 4 + hd] + edv)) : 0.f;
        float w1l = (idx1 < deg) ? __expf(leaky(es1[s1 * 4 + hd] + edv)) : 0.f;
        wsum += w0l + w1l;
        int se[8];
#pragma unroll
        for (int e = 0; e < 4; ++e) se[e] = __shfl(s0, gbase | (e << 2));
#pragma unroll
        for (int e = 4; e < 8; ++e) se[e] = __shfl(s1, gbase | ((e - 4) << 2));
        uint4 rv[8];
#pragma unroll
        for (int e = 0; e < 8; ++e)
            rv[e] = *(const uint4*)(hrow + ((size_t)(unsigned)se[e] << 8));
#pragma unroll
        for (int e = 0; e < 8; ++e) {
            int lsrc = gbase | ((e & 3) << 2);
            float wl = (e < 4) ? w0l : w1l;
            float w0 = __shfl(wl, lsrc | 0);
            float w1 = __shfl(wl, lsrc | 1);
            float w2 = __shfl(wl, lsrc | 2);
            float w3 = __shfl(wl, lsrc | 3);
            f32x2 p;
            p = __builtin_amdgcn_cvt_pk_f32_fp8((int)rv[e].x, false); a[0]  += w0 * p.x; a[1]  += w0 * p.y;
            p = __builtin_amdgcn_cvt_pk_f32_fp8((int)rv[e].x, true);  a[2]  += w0 * p.x; a[3]  += w0 * p.y;
            p = __builtin_amdgcn_cvt_pk_f32_fp8((int)rv[e].y, false); a[4]  += w1 * p.x; a[5]  += w1 * p.y;
            p = __builtin_amdgcn_cvt_pk_f32_fp8((int)rv[e].y, true);  a[6]  += w1 * p.x; a[7]  += w1 * p.y;
            p = __builtin_amdgcn_cvt_pk_f32_fp8((int)rv[e].z, false); a[8]  += w2 * p.x; a[9]  += w2 * p.y;
            p = __builtin_amdgcn_cvt_pk_f32_fp8((int)rv[e].z, true);  a[10] += w2 * p.x; a[11] += w2 * p.y;
            p = __builtin_amdgcn_cvt_pk_f32_fp8((int)rv[e].w, false); a[12] += w3 * p.x; a[13] += w3 * p.y;
            p = __builtin_amdgcn_cvt_pk_f32_fp8((int)rv[e].w, true);  a[14] += w3 * p.x; a[15] += w3 * p.y;
        }
    }
    wsum += __shfl_xor(wsum, 4);
    wsum += __shfl_xor(wsum, 8);
    float inv[4];
#pragma unroll
    for (int h = 0; h < 4; ++h) inv[h] = 1.f / __shfl(wsum, gbase | h);
#pragma unroll
    for (int i0 = 0; i0 < 4; ++i0) {
        float4 Av = *(const float4*)&A1s[q * 16 + i0 * 4];
        float4 Bv = *(const float4*)&B1s[q * 16 + i0 * 4];
        float o0 = a[i0 * 4 + 0] * inv[i0] * Av.x + Bv.x;
        float o1 = a[i0 * 4 + 1] * inv[i0] * Av.y + Bv.y;
        float o2 = a[i0 * 4 + 2] * inv[i0] * Av.z + Bv.z;
        float o3 = a[i0 * 4 + 3] * inv[i0] * Av.w + Bv.w;
        o0 = (o0 > 0.f) ? o0 : expm1f(o0);
        o1 = (o1 > 0.f) ? o1 : expm1f(o1);
        o2 = (o2 > 0.f) ? o2 : expm1f(o2);
        o3 = (o3 > 0.f) ? o3 : expm1f(o3);
        ushort4 ov;
        ov.x = f2bf(o0); ov.y = f2bf(o1); ov.z = f2bf(o2); ov.w = f2bf(o3);
        *(ushort4*)&hbt[dl][q * 16 + i0 * 4] = ov;
    }
    __syncthreads();
    // ---- phase 2: gemm2 for this 16-node tile ----
    int w = tid >> 6;
    int quad = l >> 4, col = l & 15;
    short8 af[8];
#pragma unroll
    for (int kk = 0; kk < 8; ++kk)
        af[kk] = *(const short8*)&hbt[col][kk * 32 + quad * 8];
    f32x4 acc = (f32x4){0.f, 0.f, 0.f, 0.f};
#pragma unroll
    for (int kk = 0; kk < 8; ++kk) {
        short8 b = *(const short8*)&W2Tg[(w * 16 + col) * 256 + kk * 32 + quad * 8];
        acc = __builtin_amdgcn_mfma_f32_16x16x32_bf16(af[kk], b, acc, 0, 0, 0);
    }
    float asw = a_s2[w * 16 + col], adw = a_d2[w * 16 + col];
    float esp[4], edp[4];
#pragma unroll
    for (int r = 0; r < 4; ++r) { esp[r] = acc[r] * asw; edp[r] = acc[r] * adw; }
#pragma unroll
    for (int r = 0; r < 4; ++r) {
#pragma unroll
        for (int m = 1; m <= 8; m <<= 1) {
            esp[r] += __shfl_xor(esp[r], m);
            edp[r] += __shfl_xor(edp[r], m);
        }
    }
    if (col == 0) {
#pragma unroll
        for (int r = 0; r < 4; ++r) {
            esps[w][quad * 4 + r] = esp[r];
            edps[w][quad * 4 + r] = edp[r];
        }
    }
#pragma unroll
    for (int r = 0; r < 4; ++r) {
        unsigned pk = pack4_fp8(acc[r], acc[r], acc[r], acc[r]);
        h2t[(quad * 4 + r) * 64 + col * 4 + w] = (unsigned char)(pk & 0xff);
    }
    __syncthreads();
    if (tid < 16) {
        es2[nbase + tid] = esps[0][tid] + esps[1][tid] + esps[2][tid] + esps[3][tid];
        ed2[nbase + tid] = edps[0][tid] + edps[1][tid] + edps[2][tid] + edps[3][tid];
    }
    if (tid < 64) {
        int node = tid >> 2, c = tid & 3;
        *(uint4*)&h2f8[(size_t)(nbase + node) * 64 + c * 16] = h2t4[node * 4 + c];
    }
}

// ---------------- fused GAT2 + mean-pool: 8-lane groups, 32 nodes/block ------

__global__ __launch_bounds__(256)
void k_gat2p(const unsigned char* __restrict__ h2f8, const float* __restrict__ es2,
             const float* __restrict__ ed2, const int* __restrict__ offs,
             const unsigned short* __restrict__ csr,
             const float* __restrict__ A2s, const float* __restrict__ B2s,
             const int* __restrict__ batch, float* __restrict__ pooled) {
    __shared__ float ot[32][68];
    __shared__ int gbat[32];
    int tid = threadIdx.x;
    int l = tid & 63;
    int gb8 = l & 56;                  // 8-lane group base within wave
    int p = l & 7;
    int nb = tid >> 3;                 // node index in block (0..31)
    int nbase = blockIdx.x * 32;
    int d = nbase + nb;
    bool valid = d < N_NODES;
    int dv = valid ? d : (N_NODES - 1);
    int start = offs[dv];
    int deg = valid ? (offs[dv + 1] - start) : 0;
    float edv = ed2[dv];
    const unsigned char* hrow = h2f8 + p * 8;
    float a[8];
#pragma unroll
    for (int i = 0; i < 8; ++i) a[i] = 0.f;
    float wsum = 0.f;
    for (int c0 = 0; c0 < deg; c0 += 16) {
        int idx0 = c0 + p;
        int idx1 = c0 + 8 + p;
        int s0 = csr[start + min(idx0, deg - 1)];
        int s1 = csr[start + min(idx1, deg - 1)];
        float w0l = (idx0 < deg) ? __expf(leaky(es2[s0] + edv)) : 0.f;
        float w1l = (idx1 < deg) ? __expf(leaky(es2[s1] + edv)) : 0.f;
        wsum += w0l + w1l;
        int se[16];
#pragma unroll
        for (int e = 0; e < 8; ++e) se[e] = __shfl(s0, gb8 | e);
#pragma unroll
        for (int e = 8; e < 16; ++e) se[e] = __shfl(s1, gb8 | (e - 8));
        uint2 rv[16];
#pragma unroll
        for (int e = 0; e < 16; ++e)
            rv[e] = *(const uint2*)(hrow + ((size_t)(unsigned)se[e] << 6));
#pragma unroll
        for (int e = 0; e < 16; ++e) {
            float wl = (e < 8) ? w0l : w1l;
            float we = __shfl(wl, gb8 | (e & 7));
            f32x2 pr;
            pr = __builtin_amdgcn_cvt_pk_f32_fp8((int)rv[e].x, false); a[0] += we * pr.x; a[1] += we * pr.y;
            pr = __builtin_amdgcn_cvt_pk_f32_fp8((int)rv[e].x, true);  a[2] += we * pr.x; a[3] += we * pr.y;
            pr = __builtin_amdgcn_cvt_pk_f32_fp8((int)rv[e].y, false); a[4] += we * pr.x; a[5] += we * pr.y;
            pr = __builtin_amdgcn_cvt_pk_f32_fp8((int)rv[e].y, true);  a[6] += we * pr.x; a[7] += we * pr.y;
        }
    }
    wsum += __shfl_xor(wsum, 1);
    wsum += __shfl_xor(wsum, 2);
    wsum += __shfl_xor(wsum, 4);       // group-complete denominator
    float inv = (wsum > 0.f) ? 1.f / wsum : 0.f;
    float4 Av0 = *(const float4*)&A2s[p * 8];
    float4 Bv0 = *(const float4*)&B2s[p * 8];
    float4 Av1 = *(const float4*)&A2s[p * 8 + 4];
    float4 Bv1 = *(const float4*)&B2s[p * 8 + 4];
    float4 o0, o1;
    if (valid) {
        o0.x = a[0] * inv * Av0.x + Bv0.x;
        o0.y = a[1] * inv * Av0.y + Bv0.y;
        o0.z = a[2] * inv * Av0.z + Bv0.z;
        o0.w = a[3] * inv * Av0.w + Bv0.w;
        o1.x = a[4] * inv * Av1.x + Bv1.x;
        o1.y = a[5] * inv * Av1.y + Bv1.y;
        o1.z = a[6] * inv * Av1.z + Bv1.z;
        o1.w = a[7] * inv * Av1.w + Bv1.w;
    } else {
        o0 = make_float4(0.f, 0.f, 0.f, 0.f);
        o1 = o0;
    }
    *(float4*)&ot[nb][p * 8] = o0;
    *(float4*)&ot[nb][p * 8 + 4] = o1;
    if (tid < 32) gbat[tid] = batch[min(nbase + tid, N_NODES - 1)];
    __syncthreads();
    if (tid < 64) {
        int ch = tid;
        int curg = gbat[0];
        float acc = 0.f;
#pragma unroll
        for (int n = 0; n < 32; ++n) {
            int g = gbat[n];
            if (g != curg) {
                atomicAdd(&pooled[curg * 64 + ch], acc);
                acc = 0.f;
                curg = g;
            }
            acc += ot[n][ch];
        }
        atomicAdd(&pooled[curg * 64 + ch], acc);
    }
}

// ---------------- MLP head + log_softmax (divide + slot->real mapping) -------

__device__ int lower_bound_i(const int* a, int n, int key) {
    int lo = 0, hi = n;
    while (lo < hi) {
        int mid = (lo + hi) >> 1;
        if (a[mid] < key) lo = mid + 1; else hi = mid;
    }
    return lo;
}

__global__ void k_head(const float* __restrict__ pooled, const int* __restrict__ batch,
                       const float* __restrict__ lw1, const float* __restrict__ lb1,
                       const float* __restrict__ lw2, const float* __restrict__ lb2,
                       float* __restrict__ out) {
    int g = threadIdx.x;
    if (g >= GGRAPHS) return;
    int s0 = lower_bound_i(batch, N_NODES, g);
    int s1 = lower_bound_i(batch, N_NODES, g + 1);
    int cnt = s1 - s0;
    float invc = 1.f / (float)((cnt > 0) ? cnt : 1);
    float p[64];
#pragma unroll
    for (int c = 0; c < 64; ++c) p[c] = pooled[g * 64 + c] * invc;
    float z0 = lb2[0], z1 = lb2[1], z2 = lb2[2];
    for (int j = 0; j < 32; ++j) {
        float hj = lb1[j];
#pragma unroll
        for (int c = 0; c < 64; ++c) {
            int rc = (c & 3) * 16 + (c >> 2);    // slot c holds real channel rc
            hj += p[c] * lw1[rc * 32 + j];
        }
        hj = fmaxf(hj, 0.f);
        z0 += hj * lw2[j * 3 + 0];
        z1 += hj * lw2[j * 3 + 1];
        z2 += hj * lw2[j * 3 + 2];
    }
    float m = fmaxf(z0, fmaxf(z1, z2));
    float lse = logf(expf(z0 - m) + expf(z1 - m) + expf(z2 - m)) + m;
    out[g * 3 + 0] = z0 - lse;
    out[g * 3 + 1] = z1 - lse;
    out[g * 3 + 2] = z2 - lse;
}

// ---------------- launch ----------------

extern "C" void kernel_launch(void* const* d_in, const int* in_sizes, int n_in,
                              void* d_out, int out_size, void* d_ws, size_t ws_size,
                              hipStream_t stream) {
    (void)in_sizes; (void)n_in; (void)out_size; (void)ws_size;
    const float* x    = (const float*)d_in[0];
    const int*   ei   = (const int*)d_in[1];
    const int*   batch= (const int*)d_in[2];
    const float* W1   = (const float*)d_in[3];
    const float* a_s1 = (const float*)d_in[4];
    const float* a_d1 = (const float*)d_in[5];
    const float* b1   = (const float*)d_in[6];
    const float* g1   = (const float*)d_in[7];
    const float* be1  = (const float*)d_in[8];
    const float* m1   = (const float*)d_in[9];
    const float* v1   = (const float*)d_in[10];
    const float* W2   = (const float*)d_in[11];
    const float* a_s2 = (const float*)d_in[12];
    const float* a_d2 = (const float*)d_in[13];
    const float* b2   = (const float*)d_in[14];
    const float* g2   = (const float*)d_in[15];
    const float* be2  = (const float*)d_in[16];
    const float* m2   = (const float*)d_in[17];
    const float* v2   = (const float*)d_in[18];
    const float* lw1  = (const float*)d_in[19];
    const float* lb1  = (const float*)d_in[20];
    const float* lw2  = (const float*)d_in[21];
    const float* lb2  = (const float*)d_in[22];
    float* out = (float*)d_out;

    char* ws = (char*)d_ws;
    size_t off = 0;
    auto alloc = [&](size_t bytes) -> void* {
        void* p = ws + off;
        off += (bytes + 255) & ~(size_t)255;
        return p;
    };
    float* pooled = (float*)alloc((size_t)GGRAPHS * 64 * 4);     // 16384 B
    int*   gcur   = (int*)alloc((size_t)NBUK * 4);               // -> 1024 B slot
    unsigned short* W2T = (unsigned short*)alloc((size_t)16384 * 2);
    unsigned char*  h1  = (unsigned char*)alloc((size_t)N_NODES * 256);   // fp8 perm
    unsigned char*  h2  = (unsigned char*)alloc((size_t)N_NODES * 64);    // fp8 perm
    float* es1  = (float*)alloc((size_t)N_NODES * 4 * 4);
    float* ed1  = (float*)alloc((size_t)N_NODES * 4 * 4);
    float* es2  = (float*)alloc((size_t)N_NODES * 4);
    float* ed2  = (float*)alloc((size_t)N_NODES * 4);
    float* A1s  = (float*)alloc(256 * 4);
    float* B1s  = (float*)alloc(256 * 4);
    float* A2s  = (float*)alloc(64 * 4);
    float* B2s  = (float*)alloc(64 * 4);
    int*   offs = (int*)alloc((size_t)(N_NODES + 1) * 4);
    unsigned short* csr = (unsigned short*)alloc((size_t)ETOT * 2);
    unsigned* pairs = (unsigned*)alloc((size_t)NBUK * CAPR * 4);

    const int ngat = 3125;                     // gat1g2: 16 nodes per block
    const int ngat2 = (N_NODES + 31) / 32;     // gat2p: 32 nodes per block (1563)

    hipMemsetAsync(pooled, 0, 16384 + 1024, stream);   // pooled + gcur
    k_mega<<<NMEGA, 256, 0, stream>>>(x, ei, W1, W2,
                                      b1, g1, be1, m1, v1,
                                      b2, g2, be2, m2, v2,
                                      a_s1, a_d1,
                                      W2T, A1s, B1s, A2s, B2s,
                                      gcur, pairs, h1, es1, ed1);
    k_csr<<<NBUK, 256, 0, stream>>>(pairs, gcur, offs, csr);
    k_gat1g2<<<ngat, 256, 0, stream>>>(h1, es1, ed1, offs, csr, A1s, B1s,
                                       W2T, a_s2, a_d2, h2, es2, ed2);
    k_gat2p<<<ngat2, 256, 0, stream>>>(h2, es2, ed2, offs, csr, A2s, B2s,
                                       batch, pooled);
    k_head<<<1, 64, 0, stream>>>(pooled, batch, lw1, lb1, lw2, lb2, out);
}